// Round 6
// baseline (12124.512 us; speedup 1.0000x reference)
//
#include <hip/hip_runtime.h>

typedef unsigned short u16;
typedef unsigned int u32;
typedef __bf16 bf16x8 __attribute__((ext_vector_type(8)));
typedef float f32x4 __attribute__((ext_vector_type(4)));

#define B_ 256
#define T_ 128
#define E_ 300
#define EP 320
#define H_ 2048
#define G_ 8192

// ws layout (bytes)
#define OFF_XBF   0UL
#define OFF_WIH   20971520UL
#define OFF_WHH   26214400UL
#define OFF_BIAS  59768832UL
#define OFF_BAR   59801600UL
#define OFF_HBUF  59802112UL   // 127 fresh h buffers x 1 MB

__device__ __forceinline__ u16 f2bf(float f) {
  u32 u = __builtin_bit_cast(u32, f);
  return (u16)((u + 0x7FFFu + ((u >> 16) & 1u)) >> 16);
}
__device__ __forceinline__ float sigm_f(float x) {
  return __builtin_amdgcn_rcpf(1.0f + __expf(-x));
}
__device__ __forceinline__ float tanh_f(float x) {
  return 1.0f - 2.0f * __builtin_amdgcn_rcpf(1.0f + __expf(2.0f * x));
}

// ---------------- prep: pack/convert to bf16, zero barrier flags ----------------
__global__ void prep_kernel(const float* __restrict__ x, const float* __restrict__ Wih,
                            const float* __restrict__ Whh, const float* __restrict__ bih,
                            const float* __restrict__ bhh, u16* __restrict__ xbf,
                            u16* __restrict__ wihb, u16* __restrict__ whhb,
                            float* __restrict__ biasc, u32* __restrict__ bar) {
  const long NX = (long)T_ * B_ * EP;
  const long NWIH = (long)G_ * EP;
  const long NWHH = (long)G_ * H_;
  const long NBS = G_;
  const long NBAR = T_;
  const long total = NX + NWIH + NWHH + NBS + NBAR;
  for (long q = (long)blockIdx.x * blockDim.x + threadIdx.x; q < total;
       q += (long)gridDim.x * blockDim.x) {
    long r = q;
    if (r < NX) {
      int t = (int)(r / (B_ * EP));
      int rem = (int)(r % (B_ * EP));
      int b = rem / EP, e = rem % EP;
      float v = (e < E_) ? x[((long)b * T_ + t) * E_ + e] : 0.0f;
      xbf[r] = f2bf(v);
    } else if ((r -= NX) < NWIH) {
      int n = (int)(r / EP), e = (int)(r % EP);
      wihb[r] = f2bf((e < E_) ? Wih[(long)n * E_ + e] : 0.0f);
    } else if ((r -= NWIH) < NWHH) {
      whhb[r] = f2bf(Whh[r]);   // [8192,2048] row-major == B^T layout
    } else if ((r -= NWHH) < NBS) {
      biasc[r] = bih[r] + bhh[r];
    } else {
      r -= NBS;
      bar[r] = 0;
    }
  }
}

// ---------------- main persistent LSTM kernel ----------------
// PLAIN launch (NOT cooperative: R4's 128KB-dynamic and R5's 64KB-static coop
// launches were silently rejected -> all-zero output; our grid barrier has
// been the custom relaxed-flag one since R2, so coop launch is unnecessary).
// 256 blocks x 256 thr, 1 block/CU forced by VGPR>256. Block: all 256 batch
// rows x (8 j x 4 gates). Whh slice (32n x 2048k = 128KB) fully CU-resident:
//   kc in [0,30):  60KB static LDS (safely under the 64KB workgroup limit)
//   kc in [30,64): 68 statically-indexed bf16x8 frags in VGPRs (272 VGPR),
//                  loaded once, reused all 127 steps (full unroll!)
// => zero per-step W traffic (the R2/R3 killer: ~20MB/step W refetch).
// Wih (20KB) streamed per step (L1/L2-hot, ring-3 prefetch). A (h,x):
// per-wave direct global->VGPR, ring-4 depth-3, no K-loop barriers.
// h coherence: fresh 1MB buffer per step + sc0sc1 write-through stores +
// relaxed flag barrier (R2/R3-proven). n-order {i,f}x8j | {g,o}x8j ->
// pointwise = one shfl_xor(8) pair.
__global__ void __launch_bounds__(256, 1)
lstm_kernel(const u16* __restrict__ xbf, const u16* __restrict__ wihb,
            const u16* __restrict__ whhb, const float* __restrict__ biasc,
            u16* __restrict__ hbufs, u32* __restrict__ bar, float* __restrict__ out) {
  __shared__ __align__(16) u16 wlds[32 * 960];   // 60KB: Whh kc<30, swizzled
  __shared__ u32 fv_sh;

  const int tid = threadIdx.x;
  const int l = tid & 63;
  const int w = tid >> 6;          // wave: owns batch rows 64w..64w+63
  const int bid = blockIdx.x;
  const int j0 = bid << 3;         // 8 j-cols per block
  const int v = l & 15;
  const int q = l >> 4;
  const int jj = l & 7;
  const int jc = j0 + jj;

  // ---- one-time: Whh kc<30 -> LDS (swizzle low-3 chunk bits by row&7;
  //      row stride 960 elems = 480 dwords = 0 mod 32 banks -> swizzle valid)
  for (int it = 0; it < 15; ++it) {
    int idx = it * 256 + tid;                     // 32 rows x 120 chunks
    int n = idx / 120;
    int c = idx % 120;
    int gate = ((n >> 4) << 1) + ((n >> 3) & 1);  // {i,f}x8 | {g,o}x8
    int grow = (gate << 11) + j0 + (n & 7);
    int cs = (c & ~7) | ((c ^ (n & 7)) & 7);
    *(bf16x8*)(wlds + n * 960 + cs * 8) =
        *(const bf16x8*)(whhb + (size_t)grow * 2048 + c * 8);
  }

  // ---- one-time: Whh kc in [30,64) -> 68 register fragments (static idx only)
  bf16x8 wB[68];
#pragma unroll
  for (int kc2 = 0; kc2 < 34; ++kc2)
#pragma unroll
    for (int nt = 0; nt < 2; ++nt) {
      int n = (nt << 4) + v;
      int gate = ((n >> 4) << 1) + ((n >> 3) & 1);
      int grow = (gate << 11) + j0 + (n & 7);
      wB[kc2 * 2 + nt] = *(const bf16x8*)(whhb + (size_t)grow * 2048 +
                                          ((kc2 + 30) << 5) + (q << 3));
    }

  const float bi = biasc[jc];
  const float bff = biasc[2048 + jc];
  const float bg = biasc[4096 + jc];
  const float bo = biasc[6144 + jc];

  float cst[4][4];
#pragma unroll
  for (int mi = 0; mi < 4; ++mi)
#pragma unroll
    for (int r = 0; r < 4; ++r) cst[mi][r] = 0.0f;

  __syncthreads();   // LDS W visible to all waves

#pragma unroll 1
  for (int t = 0; t < T_; ++t) {
    f32x4 acc[4][2];
#pragma unroll
    for (int mi = 0; mi < 4; ++mi)
#pragma unroll
      for (int nt = 0; nt < 2; ++nt) acc[mi][nt] = (f32x4){0.f, 0.f, 0.f, 0.f};

    // ======== x-GEMM (no h dependency: runs BEFORE barrier wait) ========
    {
      const u16* xsrc = xbf + (size_t)t * (B_ * EP);
      bf16x8 ax[4][4];
      bf16x8 wx[3][2];                   // ring-3, distance-2 (ring-2/d-2 was a bug)
      auto ldAx = [&](int kc) {
#pragma unroll
        for (int mi = 0; mi < 4; ++mi)
          ax[kc & 3][mi] = *(const bf16x8*)(xsrc +
              (size_t)((w << 6) + (mi << 4) + v) * EP + (kc << 5) + (q << 3));
      };
      auto ldWx = [&](int kc) {
#pragma unroll
        for (int nt = 0; nt < 2; ++nt) {
          int n = (nt << 4) + v;
          int gate = ((n >> 4) << 1) + ((n >> 3) & 1);
          int grow = (gate << 11) + j0 + (n & 7);
          wx[kc % 3][nt] = *(const bf16x8*)(wihb + (size_t)grow * EP +
                                            (kc << 5) + (q << 3));
        }
      };
      ldWx(0); ldAx(0); ldWx(1); ldAx(1); ldAx(2);
#pragma unroll
      for (int kc = 0; kc < 10; ++kc) {
        if (kc + 3 < 10) ldAx(kc + 3);
        if (kc + 2 < 10) ldWx(kc + 2);
#pragma unroll
        for (int mi = 0; mi < 4; ++mi) {
          acc[mi][0] = __builtin_amdgcn_mfma_f32_16x16x32_bf16(
              ax[kc & 3][mi], wx[kc % 3][0], acc[mi][0], 0, 0, 0);
          acc[mi][1] = __builtin_amdgcn_mfma_f32_16x16x32_bf16(
              ax[kc & 3][mi], wx[kc % 3][1], acc[mi][1], 0, 0, 0);
        }
      }
    }

    // ======== barrier wait + h-GEMM ========
    if (t > 0) {
      if (tid == 0) {
        u32 f;
        while ((f = __hip_atomic_load(&bar[t - 1], __ATOMIC_RELAXED,
                                      __HIP_MEMORY_SCOPE_AGENT)) < 256u)
          __builtin_amdgcn_s_sleep(2);
        fv_sh = f;
      }
      __syncthreads();
      u32 shield = fv_sh >> 31;          // == 0; data-dep blocks load hoisting
      const u16* hsrc = hbufs + (size_t)(t - 1) * (B_ * H_) + shield;

      bf16x8 ah[4][4];
      auto ldAh = [&](int kc) {
#pragma unroll
        for (int mi = 0; mi < 4; ++mi)
          ah[kc & 3][mi] = *(const bf16x8*)(hsrc +
              (size_t)((w << 6) + (mi << 4) + v) * H_ + (kc << 5) + (q << 3));
      };
      ldAh(0); ldAh(1); ldAh(2);

      // -- kc in [0,30): B from LDS (swizzled; 2-way bank alias = free)
#pragma unroll 5
      for (int kc = 0; kc < 30; ++kc) {
        ldAh(kc + 3);                     // kc+3 <= 32 < 64: no guard
        bf16x8 bfr[2];
#pragma unroll
        for (int nt = 0; nt < 2; ++nt) {
          int n = (nt << 4) + v;
          int c = (kc << 2) + q;
          int cs = (c & ~7) | ((c ^ (n & 7)) & 7);
          bfr[nt] = *(const bf16x8*)(wlds + n * 960 + cs * 8);
        }
#pragma unroll
        for (int mi = 0; mi < 4; ++mi) {
          acc[mi][0] = __builtin_amdgcn_mfma_f32_16x16x32_bf16(
              ah[kc & 3][mi], bfr[0], acc[mi][0], 0, 0, 0);
          acc[mi][1] = __builtin_amdgcn_mfma_f32_16x16x32_bf16(
              ah[kc & 3][mi], bfr[1], acc[mi][1], 0, 0, 0);
        }
      }
      // -- kc in [30,64): B from registers (MUST fully unroll: static wB idx)
#pragma unroll
      for (int kc = 30; kc < 64; ++kc) {
        if (kc + 3 < 64) ldAh(kc + 3);
#pragma unroll
        for (int mi = 0; mi < 4; ++mi) {
          acc[mi][0] = __builtin_amdgcn_mfma_f32_16x16x32_bf16(
              ah[kc & 3][mi], wB[(kc - 30) * 2 + 0], acc[mi][0], 0, 0, 0);
          acc[mi][1] = __builtin_amdgcn_mfma_f32_16x16x32_bf16(
              ah[kc & 3][mi], wB[(kc - 30) * 2 + 1], acc[mi][1], 0, 0, 0);
        }
      }
    }

    // ======== pointwise: gather 4 gates via one shfl_xor(8) pair ========
    // acc[mi][0]: v<8 = i(j=jj), v>=8 = f ; acc[mi][1]: g / o.
    u16* hnxt = hbufs + (size_t)t * (B_ * H_);
    const bool hi = (l & 8) != 0;
#pragma unroll
    for (int mi = 0; mi < 4; ++mi) {
#pragma unroll
      for (int r = 0; r < 4; ++r) {
        float a0 = acc[mi][0][r], a1 = acc[mi][1][r];
        float s0 = __shfl_xor(a0, 8, 64);
        float s1 = __shfl_xor(a1, 8, 64);
        float ipre = hi ? s0 : a0;
        float fpre = hi ? a0 : s0;
        float gpre = hi ? s1 : a1;
        float opre = hi ? a1 : s1;
        float ig = sigm_f(ipre + bi);
        float fg = sigm_f(fpre + bff);
        float gg = tanh_f(gpre + bg);
        float og = sigm_f(opre + bo);
        float c = fg * cst[mi][r] + ig * gg;
        cst[mi][r] = c;
        float h = og * tanh_f(c);
        int row = (w << 6) + (mi << 4) + (q << 2) + r;
        if (!hi) {
          if (t < T_ - 1) {
            u16 hv = f2bf(h);
            u16* hp = hnxt + (size_t)row * H_ + jc;
            asm volatile("global_store_short %0, %1, off sc0 sc1"
                         :: "v"(hp), "v"((u32)hv) : "memory");
          } else {
            out[(size_t)row * H_ + jc] = h;
          }
        }
      }
    }

    if (t < T_ - 1) {
      __builtin_amdgcn_s_waitcnt(0);      // h stores reached coherent point
      __syncthreads();                    // all 4 waves drained
      if (tid == 0)
        __hip_atomic_fetch_add(&bar[t], 1u, __ATOMIC_RELAXED,
                               __HIP_MEMORY_SCOPE_AGENT);
    }
  }
}

extern "C" void kernel_launch(void* const* d_in, const int* in_sizes, int n_in,
                              void* d_out, int out_size, void* d_ws, size_t ws_size,
                              hipStream_t stream) {
  const float* x = (const float*)d_in[0];
  const float* Wih = (const float*)d_in[1];
  const float* Whh = (const float*)d_in[2];
  const float* bih = (const float*)d_in[3];
  const float* bhh = (const float*)d_in[4];
  char* ws = (char*)d_ws;
  u16* xbf = (u16*)(ws + OFF_XBF);
  u16* wihb = (u16*)(ws + OFF_WIH);
  u16* whhb = (u16*)(ws + OFF_WHH);
  float* biasc = (float*)(ws + OFF_BIAS);
  u32* bar = (u32*)(ws + OFF_BAR);
  u16* hbufs = (u16*)(ws + OFF_HBUF);
  float* out = (float*)d_out;

  hipLaunchKernelGGL(prep_kernel, dim3(2048), dim3(256), 0, stream,
                     x, Wih, Whh, bih, bhh, xbf, wihb, whhb, biasc, bar);

  // PLAIN launch — no cooperative validation surface (R4/R5 silent rejects).
  // Grid barrier is the custom relaxed-flag one; 256 blocks at 1 block/CU
  // (VGPR>256) are co-resident on the 256 CUs.
  hipLaunchKernelGGL(lstm_kernel, dim3(256), dim3(256), 0, stream,
                     xbf, wihb, whhb, biasc, hbufs, bar, out);
}

// Round 7
// 4853.433 us; speedup vs baseline: 2.4981x; 2.4981x over previous
//
#include <hip/hip_runtime.h>

typedef unsigned short u16;
typedef unsigned int u32;
typedef __bf16 bf16x8 __attribute__((ext_vector_type(8)));
typedef float f32x4 __attribute__((ext_vector_type(4)));

#define B_ 256
#define T_ 128
#define E_ 300
#define EP 320
#define H_ 2048
#define G_ 8192

// ws layout (bytes)
#define OFF_XBF   0UL
#define OFF_WIH   20971520UL
#define OFF_WHH   26214400UL
#define OFF_BIAS  59768832UL
#define OFF_BAR   59801600UL
#define OFF_HBUF  59802112UL   // 127 fresh h buffers x 1 MB

// global->LDS staging. aux: CPOL bits SC0=1, NT=2, SC1=16 (aux=17 proven R2).
#define GLDS16(gp, sp)                                                    \
  __builtin_amdgcn_global_load_lds(                                       \
      (__attribute__((address_space(1))) void*)(void*)(gp),               \
      (__attribute__((address_space(3))) void*)(sp), 16, 0, 0)
#define GLDS16NT(gp, sp)                                                  \
  __builtin_amdgcn_global_load_lds(                                       \
      (__attribute__((address_space(1))) void*)(void*)(gp),               \
      (__attribute__((address_space(3))) void*)(sp), 16, 0, 2)

__device__ __forceinline__ u16 f2bf(float f) {
  u32 u = __builtin_bit_cast(u32, f);
  return (u16)((u + 0x7FFFu + ((u >> 16) & 1u)) >> 16);
}
__device__ __forceinline__ float sigm_f(float x) {
  return __builtin_amdgcn_rcpf(1.0f + __expf(-x));
}
__device__ __forceinline__ float tanh_f(float x) {
  return 1.0f - 2.0f * __builtin_amdgcn_rcpf(1.0f + __expf(2.0f * x));
}

// ---------------- prep: pack/convert to bf16, zero barrier flags ----------------
__global__ void prep_kernel(const float* __restrict__ x, const float* __restrict__ Wih,
                            const float* __restrict__ Whh, const float* __restrict__ bih,
                            const float* __restrict__ bhh, u16* __restrict__ xbf,
                            u16* __restrict__ wihb, u16* __restrict__ whhb,
                            float* __restrict__ biasc, u32* __restrict__ bar) {
  const long NX = (long)T_ * B_ * EP;
  const long NWIH = (long)G_ * EP;
  const long NWHH = (long)G_ * H_;
  const long NBS = G_;
  const long NBAR = T_;
  const long total = NX + NWIH + NWHH + NBS + NBAR;
  for (long q = (long)blockIdx.x * blockDim.x + threadIdx.x; q < total;
       q += (long)gridDim.x * blockDim.x) {
    long r = q;
    if (r < NX) {
      int t = (int)(r / (B_ * EP));
      int rem = (int)(r % (B_ * EP));
      int b = rem / EP, e = rem % EP;
      float v = (e < E_) ? x[((long)b * T_ + t) * E_ + e] : 0.0f;
      xbf[r] = f2bf(v);
    } else if ((r -= NX) < NWIH) {
      int n = (int)(r / EP), e = (int)(r % EP);
      wihb[r] = f2bf((e < E_) ? Wih[(long)n * E_ + e] : 0.0f);
    } else if ((r -= NWIH) < NWHH) {
      whhb[r] = f2bf(Whh[r]);   // [8192,2048] row-major == B^T layout
    } else if ((r -= NWHH) < NBS) {
      biasc[r] = bih[r] + bhh[r];
    } else {
      r -= NBS;
      bar[r] = 0;
    }
  }
}

// ---------------- main persistent LSTM kernel ----------------
// R2 structure (LDS dbuf staging via global_load_lds — best measured) + fixes:
//  * tile 64 batch x (32j x 4 gates); bid = gb*64+gn -> the 4 gb-siblings of a
//    j-slice share bid%8 (same XCD): Whh/XCD = 4MB, no cross-XCD duplication.
//  * h and x staged with NT cache policy (evict-first) so the rotating fresh
//    h buffers + x do NOT evict the L2-resident Whh (the R2/R3 20MB/step killer).
//  * W staged plain (cacheable): after step 1, staging hits L2 (~250cyc), so the
//    per-K-iter barrier drain is short.
// h coherence: fresh 1MB buffer/step (never-cached addresses) + sc0sc1
// write-through stores + relaxed flag barrier. PLAIN launch (R4/R5 coop rejects).
__global__ void __launch_bounds__(256, 1)
lstm_kernel(const u16* __restrict__ xbf, const u16* __restrict__ wihb,
            const u16* __restrict__ whhb, const float* __restrict__ biasc,
            u16* __restrict__ hbufs, u32* __restrict__ bar, float* __restrict__ out) {
  __shared__ __align__(16) u16 As[2][64 * 64];    // 16 KB: A 64 rows x 64 k
  __shared__ __align__(16) u16 Bs[2][128 * 64];   // 32 KB: B 128 n x 64 k
  __shared__ u32 fv_sh;

  const int tid = threadIdx.x;
  const int l = tid & 63;
  const int w = tid >> 6;
  const int wr = w >> 1, wj = w & 1;   // wave tile: 32m x (16j x 4 gates)
  const int bid = blockIdx.x;
  const int b0 = (bid >> 6) << 6;      // gb*64
  const int j0 = (bid & 63) << 5;      // gn*32
  const int v = l & 15;
  const int q = l >> 4;
  const int jc = j0 + (wj << 4) + v;   // output column

  const float bi = biasc[jc];
  const float bff = biasc[2048 + jc];
  const float bg = biasc[4096 + jc];
  const float bo = biasc[6144 + jc];

  float cst[2][4];
#pragma unroll
  for (int mi = 0; mi < 2; ++mi)
#pragma unroll
    for (int r = 0; r < 4; ++r) cst[mi][r] = 0.0f;

  // A staging: 8 KB = 2 issues x 256 thr x 16B. XOR-swizzle on SOURCE chunk:
  // LDS slot (row,c) holds global chunk c^(row&7) -> conflict-free b128 reads.
  auto stageA = [&](const u16* src, int strA, int kk, int p) {
    u16* Ad = &As[p][w * 512];
#pragma unroll
    for (int i = 0; i < 2; ++i) {
      int slot = i * 256 + tid;
      int row = slot >> 3;
      const u16* g = src + (size_t)row * strA + kk + (((tid & 7) ^ (row & 7)) << 3);
      GLDS16NT(g, Ad + i * 2048);            // h & x: non-temporal (protect W in L2)
    }
  };
  // B staging: 16 KB = 4 issues. LDS row nl: gate = nl>>5, jj = nl&31.
  auto stageB = [&](const u16* src, int strB, int kk, int p) {
    u16* Bd = &Bs[p][w * 512];
#pragma unroll
    for (int i = 0; i < 4; ++i) {
      int slot = i * 256 + tid;
      int nl = slot >> 3;
      int grow = ((nl >> 5) << 11) + j0 + (nl & 31);
      const u16* g = src + (size_t)grow * strB + kk + (((tid & 7) ^ (nl & 7)) << 3);
      GLDS16(g, Bd + i * 2048);              // W: cacheable, L2-resident
    }
  };

  f32x4 acc[2][4];
  auto compute = [&](int p) {
#pragma unroll
    for (int k2 = 0; k2 < 2; ++k2) {
      int cs = ((k2 << 2) + q) ^ (l & 7);    // A/B rows ≡ l&7 (mod 8)
      const u16* ap = &As[p][((wr << 5) + v) * 64 + cs * 8];
      bf16x8 a0 = *(const bf16x8*)ap;
      bf16x8 a1 = *(const bf16x8*)(ap + 1024);        // +16 m-rows
      const u16* bp = &Bs[p][((wj << 4) + v) * 64 + cs * 8];
      bf16x8 bv0 = *(const bf16x8*)bp;                // gate i
      bf16x8 bv1 = *(const bf16x8*)(bp + 2048);       // gate f (+32 n-rows)
      bf16x8 bv2 = *(const bf16x8*)(bp + 4096);       // gate g
      bf16x8 bv3 = *(const bf16x8*)(bp + 6144);       // gate o
      acc[0][0] = __builtin_amdgcn_mfma_f32_16x16x32_bf16(a0, bv0, acc[0][0], 0, 0, 0);
      acc[0][1] = __builtin_amdgcn_mfma_f32_16x16x32_bf16(a0, bv1, acc[0][1], 0, 0, 0);
      acc[0][2] = __builtin_amdgcn_mfma_f32_16x16x32_bf16(a0, bv2, acc[0][2], 0, 0, 0);
      acc[0][3] = __builtin_amdgcn_mfma_f32_16x16x32_bf16(a0, bv3, acc[0][3], 0, 0, 0);
      acc[1][0] = __builtin_amdgcn_mfma_f32_16x16x32_bf16(a1, bv0, acc[1][0], 0, 0, 0);
      acc[1][1] = __builtin_amdgcn_mfma_f32_16x16x32_bf16(a1, bv1, acc[1][1], 0, 0, 0);
      acc[1][2] = __builtin_amdgcn_mfma_f32_16x16x32_bf16(a1, bv2, acc[1][2], 0, 0, 0);
      acc[1][3] = __builtin_amdgcn_mfma_f32_16x16x32_bf16(a1, bv3, acc[1][3], 0, 0, 0);
    }
  };

  int p = 0;
#pragma unroll 1
  for (int t = 0; t < T_; ++t) {
#pragma unroll
    for (int mi = 0; mi < 2; ++mi)
#pragma unroll
      for (int g = 0; g < 4; ++g) acc[mi][g] = (f32x4){0.f, 0.f, 0.f, 0.f};

    // ---- x phase (no h dependency): before the flag wait, hides skew
    const u16* xsrc = xbf + (size_t)t * (B_ * EP) + (size_t)b0 * EP;
    stageA(xsrc, EP, 0, p);
    stageB(wihb, EP, 0, p);
    __syncthreads();
#pragma unroll 1
    for (int kx = 0; kx < 5; ++kx) {
      if (kx < 4) {
        stageA(xsrc, EP, (kx + 1) << 6, p ^ 1);
        stageB(wihb, EP, (kx + 1) << 6, p ^ 1);
      }
      compute(p);
      __syncthreads();
      p ^= 1;
    }

    // ---- h phase (skipped at t=0: h==0)
    if (t > 0) {
      if (tid == 0) {
        u32 f;
        while ((f = __hip_atomic_load(&bar[t - 1], __ATOMIC_RELAXED,
                                      __HIP_MEMORY_SCOPE_AGENT)) < 256u)
          __builtin_amdgcn_s_sleep(2);
        fv_sh = f;
      }
      __syncthreads();
      const u16* hsrc = hbufs + (size_t)(t - 1) * (B_ * H_) + (size_t)b0 * H_ +
                        (fv_sh >> 31);       // shield==0: data-dep blocks hoist
      stageA(hsrc, H_, 0, p);
      stageB(whhb, H_, 0, p);
      __syncthreads();
#pragma unroll 1
      for (int kh = 0; kh < 32; ++kh) {
        if (kh < 31) {
          stageA(hsrc, H_, (kh + 1) << 6, p ^ 1);
          stageB(whhb, H_, (kh + 1) << 6, p ^ 1);
        }
        compute(p);
        __syncthreads();
        p ^= 1;
      }
    }

    // ---- lane-local pointwise (all 4 gates in-lane); c in registers always
    u16* hnxt = hbufs + (size_t)t * (B_ * H_);
#pragma unroll
    for (int mi = 0; mi < 2; ++mi) {
#pragma unroll
      for (int r = 0; r < 4; ++r) {
        float ig = sigm_f(acc[mi][0][r] + bi);
        float fg = sigm_f(acc[mi][1][r] + bff);
        float gg = tanh_f(acc[mi][2][r] + bg);
        float og = sigm_f(acc[mi][3][r] + bo);
        float c = fg * cst[mi][r] + ig * gg;
        cst[mi][r] = c;
        float h = og * tanh_f(c);
        int row = b0 + (wr << 5) + (mi << 4) + (q << 2) + r;
        if (t < T_ - 1) {
          u16 hv = f2bf(h);
          u16* hp = hnxt + (size_t)row * H_ + jc;
          asm volatile("global_store_short %0, %1, off sc0 sc1"
                       :: "v"(hp), "v"((u32)hv) : "memory");
        } else {
          out[(size_t)row * H_ + jc] = h;
        }
      }
    }

    if (t < T_ - 1) {
      __builtin_amdgcn_s_waitcnt(0);      // h stores at coherent point
      __syncthreads();                    // all 4 waves drained
      if (tid == 0)
        __hip_atomic_fetch_add(&bar[t], 1u, __ATOMIC_RELAXED,
                               __HIP_MEMORY_SCOPE_AGENT);
    }
  }
}

extern "C" void kernel_launch(void* const* d_in, const int* in_sizes, int n_in,
                              void* d_out, int out_size, void* d_ws, size_t ws_size,
                              hipStream_t stream) {
  const float* x = (const float*)d_in[0];
  const float* Wih = (const float*)d_in[1];
  const float* Whh = (const float*)d_in[2];
  const float* bih = (const float*)d_in[3];
  const float* bhh = (const float*)d_in[4];
  char* ws = (char*)d_ws;
  u16* xbf = (u16*)(ws + OFF_XBF);
  u16* wihb = (u16*)(ws + OFF_WIH);
  u16* whhb = (u16*)(ws + OFF_WHH);
  float* biasc = (float*)(ws + OFF_BIAS);
  u32* bar = (u32*)(ws + OFF_BAR);
  u16* hbufs = (u16*)(ws + OFF_HBUF);
  float* out = (float*)d_out;

  hipLaunchKernelGGL(prep_kernel, dim3(2048), dim3(256), 0, stream,
                     x, Wih, Whh, bih, bhh, xbf, wihb, whhb, biasc, bar);

  // Plain launch (R6-proven): grid barrier is the relaxed-flag one; 256 blocks
  // co-resident on 256 CUs.
  hipLaunchKernelGGL(lstm_kernel, dim3(256), dim3(256), 0, stream,
                     xbf, wihb, whhb, biasc, hbufs, bar, out);
}